// Round 1
// baseline (313.420 us; speedup 1.0000x reference)
//
#include <hip/hip_runtime.h>

// ---------------- constants for this problem instance ----------------
#define Bm 16
#define Cc 256
#define Hh 128
#define Ww 128
#define NBOX 512
#define ENC 6400      // C*ROI*ROI
#define HID 2048
#define DIM 256
#define NCLS 80
#define MEMSZ 1024

// ---------------- ROI align -> feats (N, 6400) ----------------
__global__ __launch_bounds__(256) void roi_align_kernel(
    const float* __restrict__ rp, const int* __restrict__ bidx,
    const float* __restrict__ bboxes, float* __restrict__ feats, int N) {
  const int n = blockIdx.x;
  const int b = bidx[n];
  const float cx = bboxes[n * 4 + 0], cy = bboxes[n * 4 + 1];
  const float bw = bboxes[n * 4 + 2], bh = bboxes[n * 4 + 3];
  const float x1 = cx - bw * 0.5f, y1 = cy - bh * 0.5f;
  const float x2 = cx + bw * 0.5f, y2 = cy + bh * 0.5f;
  const float roi_w = fmaxf(x2 - x1, 1.0f), roi_h = fmaxf(y2 - y1, 1.0f);
  const float stx = roi_w / 5.0f, sty = roi_h / 5.0f;
  for (int j = threadIdx.x; j < ENC; j += 256) {
    const int c = j / 25, p = j % 25, gy = p / 5, gx = p % 5;
    const float sx = x1 + ((float)gx + 0.5f) * stx;
    const float sy = y1 + ((float)gy + 0.5f) * sty;
    const bool invalid = (sy < -1.0f) || (sy > (float)Hh) || (sx < -1.0f) || (sx > (float)Ww);
    float v = 0.0f;
    if (!invalid) {
      float y = fmaxf(sy, 0.0f), x = fmaxf(sx, 0.0f);
      int yl = (int)floorf(y), xl = (int)floorf(x);
      if (yl >= Hh - 1) y = (float)(Hh - 1);
      if (xl >= Ww - 1) x = (float)(Ww - 1);
      yl = min(yl, Hh - 1);
      xl = min(xl, Ww - 1);
      const int yh = min(yl + 1, Hh - 1), xh = min(xl + 1, Ww - 1);
      const float ly = y - (float)yl, lx = x - (float)xl;
      const float hy = 1.0f - ly, hx = 1.0f - lx;
      const float* base = rp + ((long)(b * Cc + c) << 14);
      const float v00 = base[(yl << 7) + xl];
      const float v01 = base[(yl << 7) + xh];
      const float v10 = base[(yh << 7) + xl];
      const float v11 = base[(yh << 7) + xh];
      v = v00 * hy * hx + v01 * hy * lx + v10 * ly * hx + v11 * ly * lx;
    }
    feats[(long)n * ENC + j] = v;
  }
}

// ---------------- generic fp32 NT GEMM (A MxK, B NxK, both K-major), split-K partials ----------------
// P[z][M][N] += A[m, kz..kz+kchunk] . B[n, ...]
template <int BM, int BN, int TM, int TN>
__global__ __launch_bounds__(256) void gemm_nt_partial(
    const float* __restrict__ A, const float* __restrict__ B,
    float* __restrict__ P, int M, int N, int K, int kchunk) {
  constexpr int BK = 32;
  constexpr int NX = BN / TN;  // threads along n
  __shared__ float As[BK][BM + 1];
  __shared__ float Bs[BK][BN + 1];
  const int tid = threadIdx.x;
  const int tx = tid % NX, ty = tid / NX;
  const int m0 = blockIdx.y * BM, n0 = blockIdx.x * BN;
  const long kz = (long)blockIdx.z * kchunk;

  float acc[TM][TN];
#pragma unroll
  for (int i = 0; i < TM; ++i)
#pragma unroll
    for (int j = 0; j < TN; ++j) acc[i][j] = 0.0f;

  const float* Ap = A + (long)m0 * K + kz;
  const float* Bp = B + (long)n0 * K + kz;
  constexpr int AF4 = BM * BK / (4 * 256);
  constexpr int BF4 = BN * BK / (4 * 256);

  for (int kt = 0; kt < kchunk; kt += BK) {
    float4 av[AF4], bv[BF4];
#pragma unroll
    for (int i = 0; i < AF4; ++i) {
      const int f = tid + i * 256;
      const int row = f >> 3, kc = (f & 7) * 4;
      av[i] = *(const float4*)(Ap + (long)row * K + kt + kc);
    }
#pragma unroll
    for (int i = 0; i < BF4; ++i) {
      const int f = tid + i * 256;
      const int row = f >> 3, kc = (f & 7) * 4;
      bv[i] = *(const float4*)(Bp + (long)row * K + kt + kc);
    }
    __syncthreads();
#pragma unroll
    for (int i = 0; i < AF4; ++i) {
      const int f = tid + i * 256;
      const int row = f >> 3, kc = (f & 7) * 4;
      As[kc + 0][row] = av[i].x;
      As[kc + 1][row] = av[i].y;
      As[kc + 2][row] = av[i].z;
      As[kc + 3][row] = av[i].w;
    }
#pragma unroll
    for (int i = 0; i < BF4; ++i) {
      const int f = tid + i * 256;
      const int row = f >> 3, kc = (f & 7) * 4;
      Bs[kc + 0][row] = bv[i].x;
      Bs[kc + 1][row] = bv[i].y;
      Bs[kc + 2][row] = bv[i].z;
      Bs[kc + 3][row] = bv[i].w;
    }
    __syncthreads();
#pragma unroll
    for (int kk = 0; kk < BK; ++kk) {
      float a[TM], b[TN];
#pragma unroll
      for (int u = 0; u < TM / 4; ++u) {
        const float4 t = *(const float4*)&As[kk][ty * TM + u * 4];
        a[u * 4 + 0] = t.x; a[u * 4 + 1] = t.y; a[u * 4 + 2] = t.z; a[u * 4 + 3] = t.w;
      }
#pragma unroll
      for (int v = 0; v < TN / 4; ++v) {
        const float4 t = *(const float4*)&Bs[kk][tx * TN + v * 4];
        b[v * 4 + 0] = t.x; b[v * 4 + 1] = t.y; b[v * 4 + 2] = t.z; b[v * 4 + 3] = t.w;
      }
#pragma unroll
      for (int i = 0; i < TM; ++i)
#pragma unroll
        for (int j = 0; j < TN; ++j) acc[i][j] = fmaf(a[i], b[j], acc[i][j]);
    }
  }

  float* Pp = P + (long)blockIdx.z * M * N;
#pragma unroll
  for (int i = 0; i < TM; ++i) {
#pragma unroll
    for (int j = 0; j < TN; j += 4) {
      float4 o;
      o.x = acc[i][j + 0]; o.y = acc[i][j + 1]; o.z = acc[i][j + 2]; o.w = acc[i][j + 3];
      *(float4*)(Pp + (long)(m0 + ty * TM + i) * N + n0 + tx * TN + j) = o;
    }
  }
}

// ---------------- sum split-K partials + bias + relu ----------------
__global__ __launch_bounds__(256) void reduce_bias_relu(
    const float* __restrict__ P, const float* __restrict__ bias,
    float* __restrict__ out, int MN, int Ncols, int Z) {
  const int idx = blockIdx.x * blockDim.x + threadIdx.x;
  const int e = idx * 4;
  if (e >= MN) return;
  float4 s = *(const float4*)(P + e);
  for (int z = 1; z < Z; ++z) {
    const float4 t = *(const float4*)(P + (long)z * MN + e);
    s.x += t.x; s.y += t.y; s.z += t.z; s.w += t.w;
  }
  const float4 bb = *(const float4*)(bias + (e % Ncols));
  s.x = fmaxf(s.x + bb.x, 0.0f);
  s.y = fmaxf(s.y + bb.y, 0.0f);
  s.z = fmaxf(s.z + bb.z, 0.0f);
  s.w = fmaxf(s.w + bb.w, 0.0f);
  *(float4*)(out + e) = s;
}

// ---------------- sum GEMM2 partials + bias + 1e-8, L2-normalize rows ----------------
__global__ __launch_bounds__(256) void reduce_norm_kernel(
    const float* __restrict__ P, const float* __restrict__ b2,
    float* __restrict__ out, int M, int Z) {
  const int m = blockIdx.x, d = threadIdx.x;  // DIM==256 threads
  float f = 0.0f;
  for (int z = 0; z < Z; ++z) f += P[((long)z * M + m) * DIM + d];
  f += b2[d] + 1e-8f;
  float ss = f * f;
#pragma unroll
  for (int o = 32; o > 0; o >>= 1) ss += __shfl_xor(ss, o, 64);
  __shared__ float sred[4];
  if ((d & 63) == 0) sred[d >> 6] = ss;
  __syncthreads();
  const float tot = sred[0] + sred[1] + sred[2] + sred[3];
  const float nrm = fmaxf(sqrtf(tot), 1e-12f);
  out[(long)m * DIM + d] = f / nrm;
}

// ---------------- per-class sequential scan: pos, count_new, cw ----------------
__global__ __launch_bounds__(128) void scan_classes(
    const int* __restrict__ cls, const int* __restrict__ mcount,
    const float* __restrict__ cfreq, int N, int* __restrict__ pos,
    float* __restrict__ outCNT, float* __restrict__ outCW) {
  __shared__ float sf[NCLS], sc[NCLS];
  __shared__ float s_tot, s_mean;
  const int c = threadIdx.x;
  if (c < NCLS) {
    int cnt = 0;
    const int base = mcount[c];
    for (int i = 0; i < N; ++i) {
      if (cls[i] == c) { pos[i] = (base + cnt) % MEMSZ; ++cnt; }
    }
    outCNT[c] = (float)(base + cnt);
    sf[c] = cfreq[c] + (float)cnt;
  }
  __syncthreads();
  if (c == 0) {
    float t = 0.0f;
    for (int i = 0; i < NCLS; ++i) t += sf[i];
    s_tot = t;
  }
  __syncthreads();
  if (c < NCLS) sc[c] = 1.0f / sqrtf(fmaxf(sf[c] / s_tot, 1e-8f) + 1e-8f);
  __syncthreads();
  if (c == 0) {
    float t = 0.0f;
    for (int i = 0; i < NCLS; ++i) t += sc[i];
    s_mean = t / (float)NCLS;
  }
  __syncthreads();
  if (c < NCLS) outCW[c] = sc[c] / s_mean;
}

// ---------------- memory bank copy + scatter ----------------
__global__ __launch_bounds__(256) void copy_f4(const float4* __restrict__ src,
                                               float4* __restrict__ dst, int n4) {
  const int stride = gridDim.x * blockDim.x;
  for (int i = blockIdx.x * blockDim.x + threadIdx.x; i < n4; i += stride) dst[i] = src[i];
}

__global__ __launch_bounds__(64) void scatter_rows(
    const float* __restrict__ fn, const int* __restrict__ cls,
    const int* __restrict__ pos, float* __restrict__ mb) {
  const int i = blockIdx.x, t = threadIdx.x;  // 64 threads, 4 floats each
  const long dst = ((long)cls[i] * MEMSZ + pos[i]) * DIM;
  ((float4*)(mb + dst))[t] = ((const float4*)(fn + (long)i * DIM))[t];
}

// ---------------- launch ----------------
extern "C" void kernel_launch(void* const* d_in, const int* in_sizes, int n_in,
                              void* d_out, int out_size, void* d_ws, size_t ws_size,
                              hipStream_t stream) {
  const float* rp = (const float*)d_in[0];
  const int* bidx = (const int*)d_in[1];
  const int* cls = (const int*)d_in[2];
  const float* bboxes = (const float*)d_in[3];
  const float* w1 = (const float*)d_in[6];
  const float* b1 = (const float*)d_in[7];
  const float* w2 = (const float*)d_in[8];
  const float* b2 = (const float*)d_in[9];
  const float* mbank = (const float*)d_in[10];
  const int* mcount = (const int*)d_in[11];
  const float* cfreq = (const float*)d_in[12];
  const int N = in_sizes[1];  // 512

  // workspace layout (floats)
  float* ws = (float*)d_ws;
  float* feats = ws;                         // 512*6400          = 3,276,800
  float* P1 = ws + 3276800;                  // 4*512*2048        = 4,194,304
  float* h = P1 + 4194304;                   // 512*2048          = 1,048,576
  float* P2 = P1;                            // alias (8*512*256 = 1,048,576 <= P1 size)
  int* pos = (int*)(h + 1048576);            // 512 ints

  // output layout (floats)
  float* outFN = (float*)d_out;              // 512*256
  float* outMB = outFN + (long)NBOX * DIM;   // 80*1024*256
  float* outCNT = outMB + (long)NCLS * MEMSZ * DIM;
  float* outCW = outCNT + NCLS;

  roi_align_kernel<<<N, 256, 0, stream>>>(rp, bidx, bboxes, feats, N);

  // GEMM1: (512,6400) x (2048,6400)^T -> split-K=4 partials
  gemm_nt_partial<256, 64, 8, 8><<<dim3(HID / 64, NBOX / 256, 4), 256, 0, stream>>>(
      feats, w1, P1, NBOX, HID, ENC, ENC / 4);
  reduce_bias_relu<<<(NBOX * HID / 4 + 255) / 256, 256, 0, stream>>>(
      P1, b1, h, NBOX * HID, HID, 4);

  // GEMM2: (512,2048) x (256,2048)^T -> split-K=8 partials
  gemm_nt_partial<64, 64, 4, 4><<<dim3(DIM / 64, NBOX / 64, 8), 256, 0, stream>>>(
      h, w2, P2, NBOX, DIM, HID, HID / 8);
  reduce_norm_kernel<<<NBOX, 256, 0, stream>>>(P2, b2, outFN, NBOX, 8);

  scan_classes<<<1, 128, 0, stream>>>(cls, mcount, cfreq, N, pos, outCNT, outCW);

  copy_f4<<<2048, 256, 0, stream>>>((const float4*)mbank, (float4*)outMB,
                                    NCLS * MEMSZ * DIM / 4);
  scatter_rows<<<N, 64, 0, stream>>>(outFN, cls, pos, outMB);
}

// Round 2
// 179.636 us; speedup vs baseline: 1.7448x; 1.7448x over previous
//
#include <hip/hip_runtime.h>

#define NBOX 512
#define ENC 6400      // C*ROI*ROI
#define HID 2048
#define DIM 256
#define NCLS 80
#define MEMSZ 1024
#define Bm 16
#define Cc 256
#define Hh 128
#define Ww 128

typedef __attribute__((ext_vector_type(8))) short bf16x8;
typedef __attribute__((ext_vector_type(4))) float f32x4;

__device__ __forceinline__ ushort f2bf(float x) {
  union { float f; unsigned u; } v;
  v.f = x;
  const unsigned r = v.u + 0x7fffu + ((v.u >> 16) & 1u);  // RTNE
  return (ushort)(r >> 16);
}

// ---------------- ROI align -> feats (N, 6400) in bf16 ----------------
__global__ __launch_bounds__(256) void roi_align_kernel(
    const float* __restrict__ rp, const int* __restrict__ bidx,
    const float* __restrict__ bboxes, ushort* __restrict__ feats, int N) {
  const int n = blockIdx.x;
  const int b = bidx[n];
  const float cx = bboxes[n * 4 + 0], cy = bboxes[n * 4 + 1];
  const float bw = bboxes[n * 4 + 2], bh = bboxes[n * 4 + 3];
  const float x1 = cx - bw * 0.5f, y1 = cy - bh * 0.5f;
  const float x2 = cx + bw * 0.5f, y2 = cy + bh * 0.5f;
  const float roi_w = fmaxf(x2 - x1, 1.0f), roi_h = fmaxf(y2 - y1, 1.0f);
  const float stx = roi_w / 5.0f, sty = roi_h / 5.0f;
  for (int j4 = threadIdx.x; j4 < ENC / 4; j4 += 256) {
    ushort4 o;
    float ov[4];
#pragma unroll
    for (int e = 0; e < 4; ++e) {
      const int j = j4 * 4 + e;
      const int c = j / 25, p = j % 25, gy = p / 5, gx = p % 5;
      const float sx = x1 + ((float)gx + 0.5f) * stx;
      const float sy = y1 + ((float)gy + 0.5f) * sty;
      const bool invalid = (sy < -1.0f) || (sy > (float)Hh) || (sx < -1.0f) || (sx > (float)Ww);
      float v = 0.0f;
      if (!invalid) {
        float y = fmaxf(sy, 0.0f), x = fmaxf(sx, 0.0f);
        int yl = (int)floorf(y), xl = (int)floorf(x);
        if (yl >= Hh - 1) y = (float)(Hh - 1);
        if (xl >= Ww - 1) x = (float)(Ww - 1);
        yl = min(yl, Hh - 1);
        xl = min(xl, Ww - 1);
        const int yh = min(yl + 1, Hh - 1), xh = min(xl + 1, Ww - 1);
        const float ly = y - (float)yl, lx = x - (float)xl;
        const float hy = 1.0f - ly, hx = 1.0f - lx;
        const float* base = rp + ((long)(b * Cc + c) << 14);
        const float v00 = base[(yl << 7) + xl];
        const float v01 = base[(yl << 7) + xh];
        const float v10 = base[(yh << 7) + xl];
        const float v11 = base[(yh << 7) + xh];
        v = v00 * hy * hx + v01 * hy * lx + v10 * ly * hx + v11 * ly * lx;
      }
      ov[e] = v;
    }
    o.x = f2bf(ov[0]); o.y = f2bf(ov[1]); o.z = f2bf(ov[2]); o.w = f2bf(ov[3]);
    *(ushort4*)(feats + (long)n * ENC + j4 * 4) = o;
  }
}

// ---------------- bf16 MFMA NT GEMM, split-K partials ----------------
// A: bf16 [M][K] row-major.  B: fp32 [N][K] row-major (converted while staging).
// P[z][M][N] = A[:, kz..] . B[:, kz..]^T  over kchunk.
// 256 threads = 4 waves arranged 2x2; wave tile = (TM*16) x (TN*16); BM=2*TM*16, BN=2*TN*16.
template <int BM, int BN, int TM, int TN>
__global__ __launch_bounds__(256) void gemm_bf16_nt(
    const ushort* __restrict__ A, const float* __restrict__ B,
    float* __restrict__ P, int M, int N, int K, int kchunk) {
  constexpr int IA = BM * 4 / 256;  // 16B chunks of A tile per thread
  constexpr int IB = BN * 8 / 256;  // float4 chunks of B tile per thread
  __shared__ ushort As[BM][40];     // pad 32->40 elems (80B rows, 16B-aligned)
  __shared__ ushort Bs[BN][40];
  const int tid = threadIdx.x;
  const int lane = tid & 63;
  const int wave = tid >> 6;
  const int wr = wave >> 1, wc = wave & 1;
  const int m0 = blockIdx.y * BM, n0 = blockIdx.x * BN;
  const long kz = (long)blockIdx.z * kchunk;

  f32x4 acc[TM][TN];
#pragma unroll
  for (int i = 0; i < TM; ++i)
#pragma unroll
    for (int j = 0; j < TN; ++j) acc[i][j] = (f32x4)0.0f;

  int4 areg[IA];
  float4 breg[IB];

  auto loadt = [&](int kt) {
#pragma unroll
    for (int i = 0; i < IA; ++i) {
      const int f = tid + i * 256;
      areg[i] = *(const int4*)(A + (long)(m0 + (f >> 2)) * K + kz + kt + (f & 3) * 8);
    }
#pragma unroll
    for (int i = 0; i < IB; ++i) {
      const int f = tid + i * 256;
      breg[i] = *(const float4*)(B + (long)(n0 + (f >> 3)) * K + kz + kt + (f & 7) * 4);
    }
  };
  auto storet = [&]() {
#pragma unroll
    for (int i = 0; i < IA; ++i) {
      const int f = tid + i * 256;
      *(int4*)&As[f >> 2][(f & 3) * 8] = areg[i];
    }
#pragma unroll
    for (int i = 0; i < IB; ++i) {
      const int f = tid + i * 256;
      const float4 bv = breg[i];
      ushort4 o;
      o.x = f2bf(bv.x); o.y = f2bf(bv.y); o.z = f2bf(bv.z); o.w = f2bf(bv.w);
      *(ushort4*)&Bs[f >> 3][(f & 7) * 4] = o;
    }
  };

  const int lrow = lane & 15;
  const int kb = (lane >> 4) * 8;
  const int NT = kchunk / 32;

  loadt(0);
  for (int t = 0; t < NT; ++t) {
    __syncthreads();
    storet();
    __syncthreads();
    if (t + 1 < NT) loadt((t + 1) * 32);
    bf16x8 a[TM], b[TN];
#pragma unroll
    for (int i = 0; i < TM; ++i)
      a[i] = *(const bf16x8*)&As[wr * (TM * 16) + i * 16 + lrow][kb];
#pragma unroll
    for (int j = 0; j < TN; ++j)
      b[j] = *(const bf16x8*)&Bs[wc * (TN * 16) + j * 16 + lrow][kb];
#pragma unroll
    for (int i = 0; i < TM; ++i)
#pragma unroll
      for (int j = 0; j < TN; ++j)
        acc[i][j] = __builtin_amdgcn_mfma_f32_16x16x32_bf16(a[i], b[j], acc[i][j], 0, 0, 0);
  }

  float* Pp = P + (long)blockIdx.z * M * N;
  const int r0 = m0 + wr * (TM * 16) + ((lane >> 4) << 2);
  const int c0 = n0 + wc * (TN * 16) + lrow;
#pragma unroll
  for (int i = 0; i < TM; ++i)
#pragma unroll
    for (int j = 0; j < TN; ++j)
#pragma unroll
      for (int r = 0; r < 4; ++r)
        Pp[(long)(r0 + i * 16 + r) * N + c0 + j * 16] = acc[i][j][r];
}

// ---------------- sum split-K partials + bias + relu -> bf16 ----------------
__global__ __launch_bounds__(256) void reduce_bias_relu_bf16(
    const float* __restrict__ P, const float* __restrict__ bias,
    ushort* __restrict__ out, int MN, int Ncols, int Z) {
  const int e = (blockIdx.x * 256 + threadIdx.x) * 4;
  if (e >= MN) return;
  float4 s = *(const float4*)(P + e);
  for (int z = 1; z < Z; ++z) {
    const float4 t = *(const float4*)(P + (long)z * MN + e);
    s.x += t.x; s.y += t.y; s.z += t.z; s.w += t.w;
  }
  const float4 bb = *(const float4*)(bias + (e & (Ncols - 1)));
  ushort4 o;
  o.x = f2bf(fmaxf(s.x + bb.x, 0.0f));
  o.y = f2bf(fmaxf(s.y + bb.y, 0.0f));
  o.z = f2bf(fmaxf(s.z + bb.z, 0.0f));
  o.w = f2bf(fmaxf(s.w + bb.w, 0.0f));
  *(ushort4*)(out + e) = o;
}

// ---------------- sum GEMM2 partials + bias + 1e-8, L2-normalize rows ----------------
__global__ __launch_bounds__(256) void reduce_norm_kernel(
    const float* __restrict__ P, const float* __restrict__ b2,
    float* __restrict__ out, int M, int Z) {
  const int m = blockIdx.x, d = threadIdx.x;  // DIM==256 threads
  float f = 0.0f;
  for (int z = 0; z < Z; ++z) f += P[((long)z * M + m) * DIM + d];
  f += b2[d] + 1e-8f;
  float ss = f * f;
#pragma unroll
  for (int o = 32; o > 0; o >>= 1) ss += __shfl_xor(ss, o, 64);
  __shared__ float sred[4];
  if ((d & 63) == 0) sred[d >> 6] = ss;
  __syncthreads();
  const float tot = sred[0] + sred[1] + sred[2] + sred[3];
  const float nrm = fmaxf(sqrtf(tot), 1e-12f);
  out[(long)m * DIM + d] = f / nrm;
}

// ---------------- per-class sequential scan: pos, count_new, cw ----------------
__global__ __launch_bounds__(128) void scan_classes(
    const int* __restrict__ cls, const int* __restrict__ mcount,
    const float* __restrict__ cfreq, int N, int* __restrict__ pos,
    float* __restrict__ outCNT, float* __restrict__ outCW) {
  __shared__ float sf[NCLS], sc[NCLS];
  __shared__ float s_tot, s_mean;
  const int c = threadIdx.x;
  if (c < NCLS) {
    int cnt = 0;
    const int base = mcount[c];
    for (int i = 0; i < N; ++i) {
      if (cls[i] == c) { pos[i] = (base + cnt) % MEMSZ; ++cnt; }
    }
    outCNT[c] = (float)(base + cnt);
    sf[c] = cfreq[c] + (float)cnt;
  }
  __syncthreads();
  if (c == 0) {
    float t = 0.0f;
    for (int i = 0; i < NCLS; ++i) t += sf[i];
    s_tot = t;
  }
  __syncthreads();
  if (c < NCLS) sc[c] = 1.0f / sqrtf(fmaxf(sf[c] / s_tot, 1e-8f) + 1e-8f);
  __syncthreads();
  if (c == 0) {
    float t = 0.0f;
    for (int i = 0; i < NCLS; ++i) t += sc[i];
    s_mean = t / (float)NCLS;
  }
  __syncthreads();
  if (c < NCLS) outCW[c] = sc[c] / s_mean;
}

// ---------------- memory bank copy + scatter ----------------
__global__ __launch_bounds__(256) void copy_f4(const float4* __restrict__ src,
                                               float4* __restrict__ dst, int n4) {
  const int stride = gridDim.x * blockDim.x;
  for (int i = blockIdx.x * blockDim.x + threadIdx.x; i < n4; i += stride) dst[i] = src[i];
}

__global__ __launch_bounds__(64) void scatter_rows(
    const float* __restrict__ fn, const int* __restrict__ cls,
    const int* __restrict__ pos, float* __restrict__ mb) {
  const int i = blockIdx.x, t = threadIdx.x;  // 64 threads, 4 floats each
  const long dst = ((long)cls[i] * MEMSZ + pos[i]) * DIM;
  ((float4*)(mb + dst))[t] = ((const float4*)(fn + (long)i * DIM))[t];
}

// ---------------- launch ----------------
extern "C" void kernel_launch(void* const* d_in, const int* in_sizes, int n_in,
                              void* d_out, int out_size, void* d_ws, size_t ws_size,
                              hipStream_t stream) {
  const float* rp = (const float*)d_in[0];
  const int* bidx = (const int*)d_in[1];
  const int* cls = (const int*)d_in[2];
  const float* bboxes = (const float*)d_in[3];
  const float* w1 = (const float*)d_in[6];
  const float* b1 = (const float*)d_in[7];
  const float* w2 = (const float*)d_in[8];
  const float* b2 = (const float*)d_in[9];
  const float* mbank = (const float*)d_in[10];
  const int* mcount = (const int*)d_in[11];
  const float* cfreq = (const float*)d_in[12];
  const int N = in_sizes[1];  // 512

  // workspace layout (bytes, all 16B-aligned)
  char* ws = (char*)d_ws;
  ushort* feats = (ushort*)ws;                      // 512*6400*2   = 6,553,600 B
  float* P1 = (float*)(ws + 6553600);               // 4*512*2048*4 = 16,777,216 B
  ushort* h = (ushort*)(ws + 6553600 + 16777216);   // 512*2048*2   = 2,097,152 B
  int* pos = (int*)(ws + 6553600 + 16777216 + 2097152);  // 512*4 B
  float* P2 = P1;  // alias: 16*512*256*4 = 8,388,608 B <= P1 (P1 consumed before GEMM2)

  // output layout (floats)
  float* outFN = (float*)d_out;              // 512*256
  float* outMB = outFN + (long)NBOX * DIM;   // 80*1024*256
  float* outCNT = outMB + (long)NCLS * MEMSZ * DIM;
  float* outCW = outCNT + NCLS;

  roi_align_kernel<<<N, 256, 0, stream>>>(rp, bidx, bboxes, feats, N);

  // GEMM1: (512,6400)bf16 x (2048,6400)fp32^T, split-K=4
  gemm_bf16_nt<128, 128, 4, 4><<<dim3(HID / 128, NBOX / 128, 4), 256, 0, stream>>>(
      feats, w1, P1, NBOX, HID, ENC, ENC / 4);
  reduce_bias_relu_bf16<<<(NBOX * HID / 4 + 255) / 256, 256, 0, stream>>>(
      P1, b1, h, NBOX * HID, HID, 4);

  // GEMM2: (512,2048)bf16 x (256,2048)fp32^T, split-K=16
  gemm_bf16_nt<128, 64, 4, 2><<<dim3(DIM / 64, NBOX / 128, 16), 256, 0, stream>>>(
      h, w2, P2, NBOX, DIM, HID, HID / 16);
  reduce_norm_kernel<<<NBOX, 256, 0, stream>>>(P2, b2, outFN, NBOX, 16);

  scan_classes<<<1, 128, 0, stream>>>(cls, mcount, cfreq, N, pos, outCNT, outCW);

  copy_f4<<<2048, 256, 0, stream>>>((const float4*)mbank, (float4*)outMB,
                                    NCLS * MEMSZ * DIM / 4);
  scatter_rows<<<N, 64, 0, stream>>>(outFN, cls, pos, outMB);
}

// Round 3
// 167.871 us; speedup vs baseline: 1.8670x; 1.0701x over previous
//
#include <hip/hip_runtime.h>

#define NBOX 512
#define ENC 6400      // C*ROI*ROI
#define HID 2048
#define DIM 256
#define NCLS 80
#define MEMSZ 1024
#define Bm 16
#define Cc 256
#define Hh 128
#define Ww 128

typedef __attribute__((ext_vector_type(8))) short bf16x8;
typedef __attribute__((ext_vector_type(4))) float f32x4;

__device__ __forceinline__ ushort f2bf(float x) {
  union { float f; unsigned u; } v;
  v.f = x;
  const unsigned r = v.u + 0x7fffu + ((v.u >> 16) & 1u);  // RTNE
  return (ushort)(r >> 16);
}

// ---------------- ROI align -> feats (N, 6400) in bf16 ----------------
__global__ __launch_bounds__(256) void roi_align_kernel(
    const float* __restrict__ rp, const int* __restrict__ bidx,
    const float* __restrict__ bboxes, ushort* __restrict__ feats, int N) {
  const int n = blockIdx.x;
  const int b = bidx[n];
  const float cx = bboxes[n * 4 + 0], cy = bboxes[n * 4 + 1];
  const float bw = bboxes[n * 4 + 2], bh = bboxes[n * 4 + 3];
  const float x1 = cx - bw * 0.5f, y1 = cy - bh * 0.5f;
  const float x2 = cx + bw * 0.5f, y2 = cy + bh * 0.5f;
  const float roi_w = fmaxf(x2 - x1, 1.0f), roi_h = fmaxf(y2 - y1, 1.0f);
  const float stx = roi_w / 5.0f, sty = roi_h / 5.0f;
  for (int j4 = threadIdx.x; j4 < ENC / 4; j4 += 256) {
    ushort4 o;
    float ov[4];
#pragma unroll
    for (int e = 0; e < 4; ++e) {
      const int j = j4 * 4 + e;
      const int c = j / 25, p = j % 25, gy = p / 5, gx = p % 5;
      const float sx = x1 + ((float)gx + 0.5f) * stx;
      const float sy = y1 + ((float)gy + 0.5f) * sty;
      const bool invalid = (sy < -1.0f) || (sy > (float)Hh) || (sx < -1.0f) || (sx > (float)Ww);
      float v = 0.0f;
      if (!invalid) {
        float y = fmaxf(sy, 0.0f), x = fmaxf(sx, 0.0f);
        int yl = (int)floorf(y), xl = (int)floorf(x);
        if (yl >= Hh - 1) y = (float)(Hh - 1);
        if (xl >= Ww - 1) x = (float)(Ww - 1);
        yl = min(yl, Hh - 1);
        xl = min(xl, Ww - 1);
        const int yh = min(yl + 1, Hh - 1), xh = min(xl + 1, Ww - 1);
        const float ly = y - (float)yl, lx = x - (float)xl;
        const float hy = 1.0f - ly, hx = 1.0f - lx;
        const float* base = rp + ((long)(b * Cc + c) << 14);
        const float v00 = base[(yl << 7) + xl];
        const float v01 = base[(yl << 7) + xh];
        const float v10 = base[(yh << 7) + xl];
        const float v11 = base[(yh << 7) + xh];
        v = v00 * hy * hx + v01 * hy * lx + v10 * ly * hx + v11 * ly * lx;
      }
      ov[e] = v;
    }
    o.x = f2bf(ov[0]); o.y = f2bf(ov[1]); o.z = f2bf(ov[2]); o.w = f2bf(ov[3]);
    *(ushort4*)(feats + (long)n * ENC + j4 * 4) = o;
  }
}

// ---------------- bf16 MFMA NT GEMM, split-K partials, dbuf LDS ----------------
// A: bf16 [M][K] row-major.  B: fp32 [N][K] row-major (converted while staging).
// P[z][M][N] = A . B^T over kchunk.  Blocks with blockIdx.z >= zGemm instead
// stream-copy csrc->cdst (memory-bank copy fused for HBM/compute overlap).
// WM x WN waves; wave tile (TM*16) x (TN*16); BM = WM*TM*16, BN = WN*TN*16.
template <int BM, int BN, int WM, int WN, int TM, int TN>
__global__ __launch_bounds__(WM * WN * 64) void gemm_bf16_nt(
    const ushort* __restrict__ A, const float* __restrict__ B,
    float* __restrict__ P, int M, int N, int K, int kchunk, int zGemm,
    const float4* __restrict__ csrc, float4* __restrict__ cdst, int cn4) {
  constexpr int THREADS = WM * WN * 64;
  const int tid = threadIdx.x;
  if ((int)blockIdx.z >= zGemm) {
    const int nb = (int)(gridDim.x * gridDim.y) * ((int)gridDim.z - zGemm);
    const int cb = (((int)blockIdx.z - zGemm) * (int)gridDim.y + (int)blockIdx.y) *
                       (int)gridDim.x + (int)blockIdx.x;
    for (int i = cb * THREADS + tid; i < cn4; i += nb * THREADS) cdst[i] = csrc[i];
    return;
  }
  constexpr int CA = BM * 4 / THREADS;  // int4 chunks of A tile per thread
  constexpr int CB = BN * 8 / THREADS;  // float4 chunks of B tile per thread
  __shared__ ushort As[2][BM][40];
  __shared__ ushort Bs[2][BN][40];
  const int lane = tid & 63;
  const int wave = tid >> 6;
  const int wr = wave / WN, wc = wave % WN;
  const int m0 = blockIdx.y * BM, n0 = blockIdx.x * BN;
  const long kz = (long)blockIdx.z * kchunk;

  f32x4 acc[TM][TN];
#pragma unroll
  for (int i = 0; i < TM; ++i)
#pragma unroll
    for (int j = 0; j < TN; ++j) acc[i][j] = (f32x4)0.0f;

  int4 areg[CA];
  float4 breg[CB];

  auto loadt = [&](int kt) {
#pragma unroll
    for (int i = 0; i < CA; ++i) {
      const int f = tid + i * THREADS;
      areg[i] = *(const int4*)(A + (long)(m0 + (f >> 2)) * K + kz + kt + (f & 3) * 8);
    }
#pragma unroll
    for (int i = 0; i < CB; ++i) {
      const int f = tid + i * THREADS;
      breg[i] = *(const float4*)(B + (long)(n0 + (f >> 3)) * K + kz + kt + (f & 7) * 4);
    }
  };
  auto storet = [&](int buf) {
#pragma unroll
    for (int i = 0; i < CA; ++i) {
      const int f = tid + i * THREADS;
      *(int4*)&As[buf][f >> 2][(f & 3) * 8] = areg[i];
    }
#pragma unroll
    for (int i = 0; i < CB; ++i) {
      const int f = tid + i * THREADS;
      const float4 bv = breg[i];
      ushort4 o;
      o.x = f2bf(bv.x); o.y = f2bf(bv.y); o.z = f2bf(bv.z); o.w = f2bf(bv.w);
      *(ushort4*)&Bs[buf][f >> 3][(f & 7) * 4] = o;
    }
  };

  const int lrow = lane & 15;
  const int kb = (lane >> 4) * 8;
  const int NT = kchunk / 32;

  loadt(0);
  storet(0);
  __syncthreads();
  for (int t = 0; t < NT; ++t) {
    const int cur = t & 1;
    if (t + 1 < NT) loadt((t + 1) * 32);  // prefetch issues before compute
    bf16x8 a[TM], b[TN];
#pragma unroll
    for (int i = 0; i < TM; ++i)
      a[i] = *(const bf16x8*)&As[cur][wr * (TM * 16) + i * 16 + lrow][kb];
#pragma unroll
    for (int j = 0; j < TN; ++j)
      b[j] = *(const bf16x8*)&Bs[cur][wc * (TN * 16) + j * 16 + lrow][kb];
#pragma unroll
    for (int i = 0; i < TM; ++i)
#pragma unroll
      for (int j = 0; j < TN; ++j)
        acc[i][j] = __builtin_amdgcn_mfma_f32_16x16x32_bf16(a[i], b[j], acc[i][j], 0, 0, 0);
    if (t + 1 < NT) storet(cur ^ 1);  // waits on prefetch, fills other buffer
    __syncthreads();
  }

  float* Pp = P + (long)blockIdx.z * M * N;
  const int r0 = m0 + wr * (TM * 16) + ((lane >> 4) << 2);
  const int c0 = n0 + wc * (TN * 16) + lrow;
#pragma unroll
  for (int i = 0; i < TM; ++i)
#pragma unroll
    for (int j = 0; j < TN; ++j)
#pragma unroll
      for (int r = 0; r < 4; ++r)
        Pp[(long)(r0 + i * 16 + r) * N + c0 + j * 16] = acc[i][j][r];
}

// ---------------- sum split-K partials + bias + relu -> bf16 ----------------
__global__ __launch_bounds__(256) void reduce_bias_relu_bf16(
    const float* __restrict__ P, const float* __restrict__ bias,
    ushort* __restrict__ out, int MN, int Ncols, int Z) {
  const int e = (blockIdx.x * 256 + threadIdx.x) * 4;
  if (e >= MN) return;
  float4 s = *(const float4*)(P + e);
  for (int z = 1; z < Z; ++z) {
    const float4 t = *(const float4*)(P + (long)z * MN + e);
    s.x += t.x; s.y += t.y; s.z += t.z; s.w += t.w;
  }
  const float4 bb = *(const float4*)(bias + (e & (Ncols - 1)));
  ushort4 o;
  o.x = f2bf(fmaxf(s.x + bb.x, 0.0f));
  o.y = f2bf(fmaxf(s.y + bb.y, 0.0f));
  o.z = f2bf(fmaxf(s.z + bb.z, 0.0f));
  o.w = f2bf(fmaxf(s.w + bb.w, 0.0f));
  *(ushort4*)(out + e) = o;
}

// ---------------- sum GEMM2 partials + bias + 1e-8, L2-normalize rows ----------------
__global__ __launch_bounds__(256) void reduce_norm_kernel(
    const float* __restrict__ P, const float* __restrict__ b2,
    float* __restrict__ out, int M, int Z) {
  const int m = blockIdx.x, d = threadIdx.x;  // DIM==256 threads
  float f = 0.0f;
  for (int z = 0; z < Z; ++z) f += P[((long)z * M + m) * DIM + d];
  f += b2[d] + 1e-8f;
  float ss = f * f;
#pragma unroll
  for (int o = 32; o > 0; o >>= 1) ss += __shfl_xor(ss, o, 64);
  __shared__ float sred[4];
  if ((d & 63) == 0) sred[d >> 6] = ss;
  __syncthreads();
  const float tot = sred[0] + sred[1] + sred[2] + sred[3];
  const float nrm = fmaxf(sqrtf(tot), 1e-12f);
  out[(long)m * DIM + d] = f / nrm;
}

// ---------------- per-class sequential scan: pos, count_new, cw ----------------
__global__ __launch_bounds__(128) void scan_classes(
    const int* __restrict__ cls, const int* __restrict__ mcount,
    const float* __restrict__ cfreq, int N, int* __restrict__ pos,
    float* __restrict__ outCNT, float* __restrict__ outCW) {
  __shared__ float sf[NCLS], sc[NCLS];
  __shared__ float s_tot, s_mean;
  const int c = threadIdx.x;
  if (c < NCLS) {
    int cnt = 0;
    const int base = mcount[c];
    for (int i = 0; i < N; ++i) {
      if (cls[i] == c) { pos[i] = (base + cnt) % MEMSZ; ++cnt; }
    }
    outCNT[c] = (float)(base + cnt);
    sf[c] = cfreq[c] + (float)cnt;
  }
  __syncthreads();
  if (c == 0) {
    float t = 0.0f;
    for (int i = 0; i < NCLS; ++i) t += sf[i];
    s_tot = t;
  }
  __syncthreads();
  if (c < NCLS) sc[c] = 1.0f / sqrtf(fmaxf(sf[c] / s_tot, 1e-8f) + 1e-8f);
  __syncthreads();
  if (c == 0) {
    float t = 0.0f;
    for (int i = 0; i < NCLS; ++i) t += sc[i];
    s_mean = t / (float)NCLS;
  }
  __syncthreads();
  if (c < NCLS) outCW[c] = sc[c] / s_mean;
}

__global__ __launch_bounds__(64) void scatter_rows(
    const float* __restrict__ fn, const int* __restrict__ cls,
    const int* __restrict__ pos, float* __restrict__ mb) {
  const int i = blockIdx.x, t = threadIdx.x;  // 64 threads, 4 floats each
  const long dst = ((long)cls[i] * MEMSZ + pos[i]) * DIM;
  ((float4*)(mb + dst))[t] = ((const float4*)(fn + (long)i * DIM))[t];
}

// ---------------- launch ----------------
extern "C" void kernel_launch(void* const* d_in, const int* in_sizes, int n_in,
                              void* d_out, int out_size, void* d_ws, size_t ws_size,
                              hipStream_t stream) {
  const float* rp = (const float*)d_in[0];
  const int* bidx = (const int*)d_in[1];
  const int* cls = (const int*)d_in[2];
  const float* bboxes = (const float*)d_in[3];
  const float* w1 = (const float*)d_in[6];
  const float* b1 = (const float*)d_in[7];
  const float* w2 = (const float*)d_in[8];
  const float* b2 = (const float*)d_in[9];
  const float* mbank = (const float*)d_in[10];
  const int* mcount = (const int*)d_in[11];
  const float* cfreq = (const float*)d_in[12];
  const int N = in_sizes[1];  // 512

  // workspace layout (bytes, all 16B-aligned)
  char* ws = (char*)d_ws;
  ushort* feats = (ushort*)ws;                        // 512*6400*2   = 6,553,600 B
  float* P1 = (float*)(ws + 6553600);                 // 8*512*2048*4 = 33,554,432 B
  ushort* h = (ushort*)(ws + 6553600 + 33554432);     // 512*2048*2   = 2,097,152 B
  int* pos = (int*)(ws + 6553600 + 33554432 + 2097152);
  float* P2 = P1;  // alias: 16*512*256*4 = 8,388,608 B (P1 consumed before GEMM2)

  // output layout (floats)
  float* outFN = (float*)d_out;              // 512*256
  float* outMB = outFN + (long)NBOX * DIM;   // 80*1024*256
  float* outCNT = outMB + (long)NCLS * MEMSZ * DIM;
  float* outCW = outCNT + NCLS;

  roi_align_kernel<<<N, 256, 0, stream>>>(rp, bidx, bboxes, feats, N);

  // GEMM1: (512,6400)bf16 x (2048,6400)fp32^T, split-K=8, 512 thr, 2 blk/CU.
  // z = 8,9 -> 128 fused copy blocks streaming the 84 MB memory bank.
  gemm_bf16_nt<128, 128, 2, 4, 4, 2><<<dim3(HID / 128, NBOX / 128, 10), 512, 0, stream>>>(
      feats, w1, P1, NBOX, HID, ENC, ENC / 8, 8,
      (const float4*)mbank, (float4*)outMB, NCLS * MEMSZ * DIM / 4);
  reduce_bias_relu_bf16<<<NBOX * HID / 4 / 256, 256, 0, stream>>>(
      P1, b1, h, NBOX * HID, HID, 8);

  // GEMM2: (512,2048)bf16 x (256,2048)fp32^T, split-K=16
  gemm_bf16_nt<128, 64, 2, 2, 4, 2><<<dim3(DIM / 64, NBOX / 128, 16), 256, 0, stream>>>(
      h, w2, P2, NBOX, DIM, HID, HID / 16, 16, nullptr, nullptr, 0);
  reduce_norm_kernel<<<NBOX, 256, 0, stream>>>(P2, b2, outFN, NBOX, 16);

  scan_classes<<<1, 128, 0, stream>>>(cls, mcount, cfreq, N, pos, outCNT, outCW);
  scatter_rows<<<N, 64, 0, stream>>>(outFN, cls, pos, outMB);
}

// Round 4
// 163.388 us; speedup vs baseline: 1.9183x; 1.0274x over previous
//
#include <hip/hip_runtime.h>

#define NBOX 512
#define ENC 6400      // C*ROI*ROI
#define HID 2048
#define DIM 256
#define NCLS 80
#define MEMSZ 1024
#define Bm 16
#define Cc 256
#define Hh 128
#define Ww 128

typedef __attribute__((ext_vector_type(8))) short bf16x8;
typedef __attribute__((ext_vector_type(4))) float f32x4;

__device__ __forceinline__ ushort f2bf(float x) {
  union { float f; unsigned u; } v;
  v.f = x;
  const unsigned r = v.u + 0x7fffu + ((v.u >> 16) & 1u);  // RTNE
  return (ushort)(r >> 16);
}

// ---------------- ROI align -> feats (N, 6400) bf16; block N does class scan ----------------
__global__ __launch_bounds__(256) void roi_scan_kernel(
    const float* __restrict__ rp, const int* __restrict__ bidx,
    const float* __restrict__ bboxes, ushort* __restrict__ feats, int N,
    const int* __restrict__ cls, const int* __restrict__ mcount,
    const float* __restrict__ cfreq, int* __restrict__ pos,
    float* __restrict__ outCNT, float* __restrict__ outCW) {
  const int n = blockIdx.x;
  if (n == N) {
    // ---- fused scan_classes: stage cls in LDS to avoid serial global loads ----
    __shared__ int scls[NBOX];
    __shared__ float sf[NCLS], sc[NCLS];
    __shared__ float s_tot, s_mean;
    const int t = threadIdx.x;
    if (t < 128) *(int4*)&scls[t * 4] = *(const int4*)&cls[t * 4];
    __syncthreads();
    if (t < NCLS) {
      int cnt = 0;
      const int base = mcount[t];
      for (int i = 0; i < N; ++i) {
        if (scls[i] == t) { pos[i] = (base + cnt) % MEMSZ; ++cnt; }
      }
      outCNT[t] = (float)(base + cnt);
      sf[t] = cfreq[t] + (float)cnt;
    }
    __syncthreads();
    if (t == 0) {
      float s = 0.0f;
      for (int i = 0; i < NCLS; ++i) s += sf[i];
      s_tot = s;
    }
    __syncthreads();
    if (t < NCLS) sc[t] = 1.0f / sqrtf(fmaxf(sf[t] / s_tot, 1e-8f) + 1e-8f);
    __syncthreads();
    if (t == 0) {
      float s = 0.0f;
      for (int i = 0; i < NCLS; ++i) s += sc[i];
      s_mean = s / (float)NCLS;
    }
    __syncthreads();
    if (t < NCLS) outCW[t] = sc[t] / s_mean;
    return;
  }
  const int b = bidx[n];
  const float cx = bboxes[n * 4 + 0], cy = bboxes[n * 4 + 1];
  const float bw = bboxes[n * 4 + 2], bh = bboxes[n * 4 + 3];
  const float x1 = cx - bw * 0.5f, y1 = cy - bh * 0.5f;
  const float x2 = cx + bw * 0.5f, y2 = cy + bh * 0.5f;
  const float roi_w = fmaxf(x2 - x1, 1.0f), roi_h = fmaxf(y2 - y1, 1.0f);
  const float stx = roi_w / 5.0f, sty = roi_h / 5.0f;
  for (int j4 = threadIdx.x; j4 < ENC / 4; j4 += 256) {
    ushort4 o;
    float ov[4];
#pragma unroll
    for (int e = 0; e < 4; ++e) {
      const int j = j4 * 4 + e;
      const int c = j / 25, p = j % 25, gy = p / 5, gx = p % 5;
      const float sx = x1 + ((float)gx + 0.5f) * stx;
      const float sy = y1 + ((float)gy + 0.5f) * sty;
      const bool invalid = (sy < -1.0f) || (sy > (float)Hh) || (sx < -1.0f) || (sx > (float)Ww);
      float v = 0.0f;
      if (!invalid) {
        float y = fmaxf(sy, 0.0f), x = fmaxf(sx, 0.0f);
        int yl = (int)floorf(y), xl = (int)floorf(x);
        if (yl >= Hh - 1) y = (float)(Hh - 1);
        if (xl >= Ww - 1) x = (float)(Ww - 1);
        yl = min(yl, Hh - 1);
        xl = min(xl, Ww - 1);
        const int yh = min(yl + 1, Hh - 1), xh = min(xl + 1, Ww - 1);
        const float ly = y - (float)yl, lx = x - (float)xl;
        const float hy = 1.0f - ly, hx = 1.0f - lx;
        const float* base = rp + ((long)(b * Cc + c) << 14);
        const float v00 = base[(yl << 7) + xl];
        const float v01 = base[(yl << 7) + xh];
        const float v10 = base[(yh << 7) + xl];
        const float v11 = base[(yh << 7) + xh];
        v = v00 * hy * hx + v01 * hy * lx + v10 * ly * hx + v11 * ly * lx;
      }
      ov[e] = v;
    }
    o.x = f2bf(ov[0]); o.y = f2bf(ov[1]); o.z = f2bf(ov[2]); o.w = f2bf(ov[3]);
    *(ushort4*)(feats + (long)n * ENC + j4 * 4) = o;
  }
}

// ---------------- bf16 MFMA NT GEMM, split-K partials, dbuf LDS, fused copy ----------------
// A: bf16 [M][K] row-major.  B: fp32 [N][K] row-major (converted while staging).
// Blocks with blockIdx.z >= zGemm stream-copy csrc->cdst (memory-bank copy).
// WM x WN waves; wave tile (TM*16) x (TN*16); BM = WM*TM*16, BN = WN*TN*16.
template <int BM, int BN, int WM, int WN, int TM, int TN>
__global__ __launch_bounds__(WM * WN * 64, 2) void gemm_bf16_nt(
    const ushort* __restrict__ A, const float* __restrict__ B,
    float* __restrict__ P, int M, int N, int K, int kchunk, int zGemm,
    const float4* __restrict__ csrc, float4* __restrict__ cdst, int cn4) {
  constexpr int THREADS = WM * WN * 64;
  const int tid = threadIdx.x;
  if ((int)blockIdx.z >= zGemm) {
    const int nb = (int)(gridDim.x * gridDim.y) * ((int)gridDim.z - zGemm);
    const int cb = (((int)blockIdx.z - zGemm) * (int)gridDim.y + (int)blockIdx.y) *
                       (int)gridDim.x + (int)blockIdx.x;
    for (int i = cb * THREADS + tid; i < cn4; i += nb * THREADS) cdst[i] = csrc[i];
    return;
  }
  constexpr int CA = BM * 4 / THREADS;  // int4 chunks of A tile per thread
  constexpr int CB = BN * 8 / THREADS;  // float4 chunks of B tile per thread
  __shared__ ushort As[2][BM][40];
  __shared__ ushort Bs[2][BN][40];
  const int lane = tid & 63;
  const int wave = tid >> 6;
  const int wr = wave / WN, wc = wave % WN;
  const int m0 = blockIdx.y * BM, n0 = blockIdx.x * BN;
  const long kz = (long)blockIdx.z * kchunk;

  f32x4 acc[TM][TN];
#pragma unroll
  for (int i = 0; i < TM; ++i)
#pragma unroll
    for (int j = 0; j < TN; ++j) acc[i][j] = (f32x4)0.0f;

  int4 areg[CA];
  float4 breg[CB];

  auto loadt = [&](int kt) {
#pragma unroll
    for (int i = 0; i < CA; ++i) {
      const int f = tid + i * THREADS;
      areg[i] = *(const int4*)(A + (long)(m0 + (f >> 2)) * K + kz + kt + (f & 3) * 8);
    }
#pragma unroll
    for (int i = 0; i < CB; ++i) {
      const int f = tid + i * THREADS;
      breg[i] = *(const float4*)(B + (long)(n0 + (f >> 3)) * K + kz + kt + (f & 7) * 4);
    }
  };
  auto storet = [&](int buf) {
#pragma unroll
    for (int i = 0; i < CA; ++i) {
      const int f = tid + i * THREADS;
      *(int4*)&As[buf][f >> 2][(f & 3) * 8] = areg[i];
    }
#pragma unroll
    for (int i = 0; i < CB; ++i) {
      const int f = tid + i * THREADS;
      const float4 bv = breg[i];
      ushort4 o;
      o.x = f2bf(bv.x); o.y = f2bf(bv.y); o.z = f2bf(bv.z); o.w = f2bf(bv.w);
      *(ushort4*)&Bs[buf][f >> 3][(f & 7) * 4] = o;
    }
  };

  const int lrow = lane & 15;
  const int kb = (lane >> 4) * 8;
  const int NT = kchunk / 32;

  loadt(0);
  storet(0);
  __syncthreads();
  for (int t = 0; t < NT; ++t) {
    const int cur = t & 1;
    if (t + 1 < NT) loadt((t + 1) * 32);  // prefetch issues before compute
    bf16x8 a[TM], b[TN];
#pragma unroll
    for (int i = 0; i < TM; ++i)
      a[i] = *(const bf16x8*)&As[cur][wr * (TM * 16) + i * 16 + lrow][kb];
#pragma unroll
    for (int j = 0; j < TN; ++j)
      b[j] = *(const bf16x8*)&Bs[cur][wc * (TN * 16) + j * 16 + lrow][kb];
#pragma unroll
    for (int i = 0; i < TM; ++i)
#pragma unroll
      for (int j = 0; j < TN; ++j)
        acc[i][j] = __builtin_amdgcn_mfma_f32_16x16x32_bf16(a[i], b[j], acc[i][j], 0, 0, 0);
    if (t + 1 < NT) storet(cur ^ 1);  // waits on prefetch, fills other buffer
    __syncthreads();
  }

  float* Pp = P + (long)blockIdx.z * M * N;
  const int r0 = m0 + wr * (TM * 16) + ((lane >> 4) << 2);
  const int c0 = n0 + wc * (TN * 16) + lrow;
#pragma unroll
  for (int i = 0; i < TM; ++i)
#pragma unroll
    for (int j = 0; j < TN; ++j)
#pragma unroll
      for (int r = 0; r < 4; ++r)
        Pp[(long)(r0 + i * 16 + r) * N + c0 + j * 16] = acc[i][j][r];
}

// ---------------- sum split-K partials + bias + relu -> bf16 ----------------
__global__ __launch_bounds__(256) void reduce_bias_relu_bf16(
    const float* __restrict__ P, const float* __restrict__ bias,
    ushort* __restrict__ out, int MN, int Ncols, int Z) {
  const int e = (blockIdx.x * 256 + threadIdx.x) * 4;
  if (e >= MN) return;
  float4 s = *(const float4*)(P + e);
  for (int z = 1; z < Z; ++z) {
    const float4 t = *(const float4*)(P + (long)z * MN + e);
    s.x += t.x; s.y += t.y; s.z += t.z; s.w += t.w;
  }
  const float4 bb = *(const float4*)(bias + (e & (Ncols - 1)));
  ushort4 o;
  o.x = f2bf(fmaxf(s.x + bb.x, 0.0f));
  o.y = f2bf(fmaxf(s.y + bb.y, 0.0f));
  o.z = f2bf(fmaxf(s.z + bb.z, 0.0f));
  o.w = f2bf(fmaxf(s.w + bb.w, 0.0f));
  *(ushort4*)(out + e) = o;
}

// ---------------- GEMM2 partials + bias + 1e-8, L2-normalize, write outFN + scatter ----------------
__global__ __launch_bounds__(256) void reduce_norm_scatter(
    const float* __restrict__ P, const float* __restrict__ b2,
    float* __restrict__ outFN, float* __restrict__ outMB,
    const int* __restrict__ cls, const int* __restrict__ pos, int M, int Z) {
  const int m = blockIdx.x, d = threadIdx.x;  // DIM==256 threads
  float f = 0.0f;
  for (int z = 0; z < Z; ++z) f += P[((long)z * M + m) * DIM + d];
  f += b2[d] + 1e-8f;
  float ss = f * f;
#pragma unroll
  for (int o = 32; o > 0; o >>= 1) ss += __shfl_xor(ss, o, 64);
  __shared__ float sred[4];
  if ((d & 63) == 0) sred[d >> 6] = ss;
  __syncthreads();
  const float tot = sred[0] + sred[1] + sred[2] + sred[3];
  const float nrm = fmaxf(sqrtf(tot), 1e-12f);
  const float r = f / nrm;
  outFN[(long)m * DIM + d] = r;
  outMB[((long)cls[m] * MEMSZ + pos[m]) * DIM + d] = r;
}

// ---------------- launch ----------------
extern "C" void kernel_launch(void* const* d_in, const int* in_sizes, int n_in,
                              void* d_out, int out_size, void* d_ws, size_t ws_size,
                              hipStream_t stream) {
  const float* rp = (const float*)d_in[0];
  const int* bidx = (const int*)d_in[1];
  const int* cls = (const int*)d_in[2];
  const float* bboxes = (const float*)d_in[3];
  const float* w1 = (const float*)d_in[6];
  const float* b1 = (const float*)d_in[7];
  const float* w2 = (const float*)d_in[8];
  const float* b2 = (const float*)d_in[9];
  const float* mbank = (const float*)d_in[10];
  const int* mcount = (const int*)d_in[11];
  const float* cfreq = (const float*)d_in[12];
  const int N = in_sizes[1];  // 512

  // workspace layout (bytes, all 16B-aligned)
  char* ws = (char*)d_ws;
  ushort* feats = (ushort*)ws;                        // 512*6400*2   = 6,553,600 B
  float* P1 = (float*)(ws + 6553600);                 // 4*512*2048*4 = 16,777,216 B
  ushort* h = (ushort*)(ws + 6553600 + 16777216);     // 512*2048*2   = 2,097,152 B
  int* pos = (int*)(ws + 6553600 + 16777216 + 2097152);
  float* P2 = P1;  // alias: 8*512*256*4 = 4,194,304 B (P1 consumed before GEMM2)

  // output layout (floats)
  float* outFN = (float*)d_out;              // 512*256
  float* outMB = outFN + (long)NBOX * DIM;   // 80*1024*256
  float* outCNT = outMB + (long)NCLS * MEMSZ * DIM;
  float* outCW = outCNT + NCLS;

  // ROI align (blocks 0..N-1) + class scan (block N)
  roi_scan_kernel<<<N + 1, 256, 0, stream>>>(rp, bidx, bboxes, feats, N,
                                             cls, mcount, cfreq, pos, outCNT, outCW);

  // GEMM1: 256^2 tiles, 8 waves, wave-tile 128x64 (MFMA-bound), split-K=4.
  // z=4..15 -> 192 fused copy blocks streaming the 84 MB memory bank. 256 blocks total.
  gemm_bf16_nt<256, 256, 2, 4, 8, 4><<<dim3(HID / 256, NBOX / 256, 16), 512, 0, stream>>>(
      feats, w1, P1, NBOX, HID, ENC, ENC / 4, 4,
      (const float4*)mbank, (float4*)outMB, NCLS * MEMSZ * DIM / 4);
  reduce_bias_relu_bf16<<<NBOX * HID / 4 / 256, 256, 0, stream>>>(
      P1, b1, h, NBOX * HID, HID, 4);

  // GEMM2: (512,2048)bf16 x (256,2048)fp32^T, split-K=8, NT=8
  gemm_bf16_nt<128, 64, 2, 2, 4, 2><<<dim3(DIM / 64, NBOX / 128, 8), 256, 0, stream>>>(
      h, w2, P2, NBOX, DIM, HID, HID / 8, 8, nullptr, nullptr, 0);

  // reduce + bias + normalize + write feat_norm + scatter into bank
  reduce_norm_scatter<<<NBOX, 256, 0, stream>>>(P2, b2, outFN, outMB, cls, pos, NBOX, 8);
}